// Round 10
// baseline (1597.334 us; speedup 1.0000x reference)
//
#include <hip/hip_runtime.h>

typedef unsigned long long ull;

// SLAYER SRM-alpha constants (f64-computed, f32-cast):
__device__ constexpr float C1f = (float)1.80967483607191914632;   // 2*exp(-0.1)
__device__ constexpr float C2f = (float)0.81873075307798185867;   // exp(-0.2)
__device__ constexpr float C3f = (float)0.24596031111569496638;   // e^0.9/10

__device__ __forceinline__ float iir_spike_step(float acc, float& y1, float& y2, float& xp,
                                                float& r1, float& r2, float& sp) {
#pragma clang fp contract(off)
    float u = C1f * y1 - C2f * y2 + C3f * xp;   // psp output at t (uses x[t-1])
    float r = C1f * r1 - C2f * r2 + C3f * sp;   // alpha response to past spikes
    float s = (u - 20.0f * r >= 10.0f) ? 1.0f : 0.0f;
    y2 = y1; y1 = u; xp = acc;
    r2 = r1; r1 = r; sp = s;
    return s;
}

// Batched sparse accumulate over a wave-uniform mask: 8-deep (then 1-deep tail)
// independent loads in flight; adds strictly ascending c (bit-exact vs serial walk).
template <int STRIDE>
__device__ __forceinline__ void sacc(float& acc, ull m, const float* __restrict__ ptr) {
    while (m) {
        ull m1 = m & (m - 1);
        ull m2 = m1 & (m1 - 1);
        ull m3 = m2 & (m2 - 1);
        ull m4 = m3 & (m3 - 1);
        ull m5 = m4 & (m4 - 1);
        ull m6 = m5 & (m5 - 1);
        ull m7 = m6 & (m6 - 1);
        if (m7) {
            float w0 = ptr[__builtin_ctzll(m)  * STRIDE];
            float w1 = ptr[__builtin_ctzll(m1) * STRIDE];
            float w2 = ptr[__builtin_ctzll(m2) * STRIDE];
            float w3 = ptr[__builtin_ctzll(m3) * STRIDE];
            float w4 = ptr[__builtin_ctzll(m4) * STRIDE];
            float w5 = ptr[__builtin_ctzll(m5) * STRIDE];
            float w6 = ptr[__builtin_ctzll(m6) * STRIDE];
            float w7 = ptr[__builtin_ctzll(m7) * STRIDE];
            acc += w0; acc += w1; acc += w2; acc += w3;
            acc += w4; acc += w5; acc += w6; acc += w7;
            m = m7 & (m7 - 1);
        } else if (m3) {
            float w0 = ptr[__builtin_ctzll(m)  * STRIDE];
            float w1 = ptr[__builtin_ctzll(m1) * STRIDE];
            float w2 = ptr[__builtin_ctzll(m2) * STRIDE];
            float w3 = ptr[__builtin_ctzll(m3) * STRIDE];
            acc += w0; acc += w1; acc += w2; acc += w3;
            m = m4;
        } else {
            acc += ptr[__builtin_ctzll(m) * STRIDE];
            m = m1;
        }
    }
}

// ---------------- SP0: pool(2x2 of s_in) + psp + spike -> w-packed row masks
__global__ void k_sp0(const float* __restrict__ s_in, ull* __restrict__ s0m) {
    int wid = (blockIdx.x * 256 + threadIdx.x) >> 6;   // 0..511 = (b,c,h)
    int lane = threadIdx.x & 63;                        // w
    int h = wid & 63;
    int c = (wid >> 6) & 1;
    int b = wid >> 7;
    const float* p00 = s_in + ((size_t)(((b * 2 + c) * 128 + 2 * h) * 128 + 2 * lane)) * 100;
    const float* p01 = p00 + 100;
    const float* p10 = p00 + 12800;
    const float* p11 = p10 + 100;
    float y1 = 0, y2 = 0, xp = 0, r1 = 0, r2 = 0, sp = 0;
    for (int t = 0; t < 100; ++t) {
        float cnt = (p00[t] > 0.5f) + (p01[t] > 0.5f) + (p10[t] > 0.5f) + (p11[t] > 0.5f);
        float s = iir_spike_step(11.0f * cnt, y1, y2, xp, r1, r2, sp);
        ull m = __ballot(s > 0.5f);
        if (lane == 0) s0m[((size_t)(t * 4 + b) * 2 + c) * 64 + h] = m;
    }
}

// ---------------- SC1: 5x5 conv (2ch) via register weights + bit-FMA (no LDS)
// acc = fma((float)bit_j, w_j, acc): exact (w*1=w, acc+0=acc), non-divergent.
// NEW s1m layout: [t][b][h][o] ulong (bit w) -> coalesced consumption in SP1.
__global__ void k_sc1(const ull* __restrict__ s0m, const float* __restrict__ w1,
                      ull* __restrict__ s1m) {
    int hg = blockIdx.x & 15;
    int o  = (blockIdx.x >> 4) & 31;
    int b  = blockIdx.x >> 9;
    float wr[50];                           // wave-uniform -> scalar regs
#pragma unroll
    for (int i = 0; i < 50; ++i) wr[i] = w1[o * 50 + i];
    int h = hg * 4 + (threadIdx.x >> 6);
    int lane = threadIdx.x & 63;            // w
    int sh = lane - 2;
    float y1 = 0, y2 = 0, xp = 0, r1 = 0, r2 = 0, sp = 0;
    for (int t = 0; t < 100; ++t) {
        float acc = 0.0f;
        const ull* rb = s0m + (size_t)(t * 4 + b) * 128;
#pragma unroll
        for (int c = 0; c < 2; ++c) {
#pragma unroll
            for (int kh = 0; kh < 5; ++kh) {
                int ih = h - 2 + kh;
                ull m = (ih >= 0 && ih < 64) ? rb[c * 64 + ih] : 0ULL;
                unsigned pat = (sh >= 0) ? ((unsigned)(m >> sh) & 31u)
                                         : (((unsigned)m << (-sh)) & 31u);
#pragma unroll
                for (int j = 0; j < 5; ++j)                     // ascending kw, exact
                    acc = fmaf((float)((pat >> j) & 1u), wr[c * 25 + kh * 5 + j], acc);
            }
        }
        float s = iir_spike_step(acc, y1, y2, xp, r1, r2, sp);
        ull mm = __ballot(s > 0.5f);
        if (lane == 0) s1m[((size_t)(t * 4 + b) * 64 + h) * 32 + o] = mm;
    }
}

// ---------------- SP1: pool SC1 spikes -> c-packed masks s2m [t][b][32][32] uint (bit c)
// s1m is [t][b][h][o]: the 32 c-lanes read 32 consecutive ulls (coalesced).
__global__ void k_sp1(const ull* __restrict__ s1m, unsigned* __restrict__ s2m) {
    int wid = (blockIdx.x * 256 + threadIdx.x) >> 6;   // (b*32+ho)*16+wop
    int lane = threadIdx.x & 63;
    int wop = wid & 15;
    int ho = (wid >> 4) & 31;
    int b = wid >> 9;
    int c = lane & 31;
    int q = lane >> 5;
    int w = wop * 2 + q;                                // output wo
    float y1 = 0, y2 = 0, xp = 0, r1 = 0, r2 = 0, sp = 0;
    for (int t = 0; t < 100; ++t) {
        const ull* base = s1m + ((size_t)(t * 4 + b) * 64 + 2 * ho) * 32 + c;
        ull m0 = base[0], m1 = base[32];
        unsigned v0 = (unsigned)(m0 >> (2 * w)) & 3u;
        unsigned v1 = (unsigned)(m1 >> (2 * w)) & 3u;
        float cnt = (float)((v0 & 1) + (v0 >> 1) + (v1 & 1) + (v1 >> 1));
        float s = iir_spike_step(11.0f * cnt, y1, y2, xp, r1, r2, sp);
        ull mm = __ballot(s > 0.5f);
        if (lane == 0)  s2m[((size_t)(t * 4 + b) * 32 + ho) * 32 + wop * 2]     = (unsigned)mm;
        if (lane == 32) s2m[((size_t)(t * 4 + b) * 32 + ho) * 32 + wop * 2 + 1] = (unsigned)(mm >> 32);
    }
}

// ---------------- weight transposes into ws: wT[pos][c][o]
__global__ void k_wT(const float* __restrict__ w2, const float* __restrict__ w3,
                     float* __restrict__ w2T, float* __restrict__ w3T) {
    int i = blockIdx.x * 256 + threadIdx.x;
    if (i < 9 * 32 * 64) {
        int o = i & 63; int c = (i >> 6) & 31; int p = i >> 11;
        w2T[i] = w2[(o * 32 + c) * 9 + p];
    }
    if (i < 9 * 64 * 128) {
        int o = i & 127; int c = (i >> 7) & 63; int p = i >> 13;
        w3T[i] = w3[(o * 64 + c) * 9 + p];
    }
}

// ---------------- transpose wf4a [512][8192] -> wT4a [8192][512], 64x64 LDS tiles
__global__ void k_wT4a(const float* __restrict__ w, float* __restrict__ wT) {
    __shared__ float tile[64][65];
    int ft = blockIdx.x & 127;   // f tile
    int ot = blockIdx.x >> 7;    // o tile (0..7)
    int j = threadIdx.x & 63;
    int i0 = threadIdx.x >> 6;   // 0..3
    for (int i = i0; i < 64; i += 4)
        tile[i][j] = w[(size_t)(ot * 64 + i) * 8192 + ft * 64 + j];
    __syncthreads();
    for (int i = i0; i < 64; i += 4)
        wT[(size_t)(ft * 64 + i) * 512 + ot * 64 + j] = tile[j][i];
}

// ---------------- SC2: sparse 3x3 conv (32c -> 64o), full-LDS weights (72KB dynamic)
// 256 blocks x 1024 thr (16 waves/CU).
__global__ __launch_bounds__(1024) void k_sc2(const unsigned* __restrict__ s2m,
                                              const float* __restrict__ w2T,
                                              ull* __restrict__ sc2m) {
    extern __shared__ float wl[];
    for (int i = threadIdx.x; i < 9 * 32 * 64; i += 1024) wl[i] = w2T[i];
    __syncthreads();
    int task = blockIdx.x * 16 + (threadIdx.x >> 6);   // 0..4095
    int pix = task & 1023;
    int b = task >> 10;
    int h = pix >> 5, w = pix & 31;
    int lane = threadIdx.x & 63;   // o
    float y1 = 0, y2 = 0, xp = 0, r1 = 0, r2 = 0, sp = 0;
    for (int t = 0; t < 100; ++t) {
        const unsigned* mb = s2m + (size_t)(t * 4 + b) * 1024;
        float acc = 0.0f;
#pragma unroll
        for (int kh = 0; kh < 3; ++kh) {
            int ih = h - 1 + kh;
            if (ih < 0 || ih >= 32) continue;
#pragma unroll
            for (int kw = 0; kw < 3; ++kw) {
                int iw = w - 1 + kw;
                if (iw < 0 || iw >= 32) continue;
                unsigned m = __builtin_amdgcn_readfirstlane(mb[ih * 32 + iw]);
                sacc<64>(acc, (ull)m, wl + (kh * 3 + kw) * 2048 + lane);
            }
        }
        float s = iir_spike_step(acc, y1, y2, xp, r1, r2, sp);
        ull mm = __ballot(s > 0.5f);
        if (lane == 0) sc2m[(size_t)(t * 4 + b) * 1024 + pix] = mm;
    }
}

// ---------------- SP2: pool SC2 masks -> s3m [t][b][16][16] ulong (bit c of 64)
__global__ void k_sp2(const ull* __restrict__ sc2m, ull* __restrict__ s3m) {
    int wid = (blockIdx.x * 256 + threadIdx.x) >> 6;   // (b*16+ho)*16+wo
    int lane = threadIdx.x & 63;                        // c
    int wo = wid & 15;
    int ho = (wid >> 4) & 15;
    int b = wid >> 8;
    float y1 = 0, y2 = 0, xp = 0, r1 = 0, r2 = 0, sp = 0;
    for (int t = 0; t < 100; ++t) {
        const ull* mb = sc2m + (size_t)(t * 4 + b) * 1024 + (2 * ho) * 32 + 2 * wo;
        ull a0 = mb[0], a1 = mb[1], a2 = mb[32], a3 = mb[33];
        float cnt = (float)(((a0 >> lane) & 1) + ((a1 >> lane) & 1) +
                            ((a2 >> lane) & 1) + ((a3 >> lane) & 1));
        float s = iir_spike_step(11.0f * cnt, y1, y2, xp, r1, r2, sp);
        ull mm = __ballot(s > 0.5f);
        if (lane == 0) s3m[(size_t)(t * 4 + b) * 256 + ho * 16 + wo] = mm;
    }
}

// ---------------- SC3: sparse 3x3 conv (64c -> 128o, o-half per block), full-LDS (144KB dyn)
// 256 blocks x 512 thr (8 waves/CU).
__global__ __launch_bounds__(512) void k_sc3(const ull* __restrict__ s3m,
                                             const float* __restrict__ w3T,
                                             ull* __restrict__ s4m) {
    extern __shared__ float wl[];
    int half = blockIdx.x & 1;
    int rest = blockIdx.x >> 1;          // 0..127 = b*32 + pg
    int pg = rest & 31;
    int b = rest >> 5;
    for (int i = threadIdx.x; i < 9 * 64 * 64; i += 512) {
        int o = i & 63; int pc = i >> 6;               // pc = p*64+c
        wl[i] = w3T[pc * 128 + half * 64 + o];
    }
    __syncthreads();
    int pix = pg * 8 + (threadIdx.x >> 6);
    int h = pix >> 4, w = pix & 15;
    int lane = threadIdx.x & 63;   // o within half
    float y1 = 0, y2 = 0, xp = 0, r1 = 0, r2 = 0, sp = 0;
    for (int t = 0; t < 100; ++t) {
        const ull* mb = s3m + (size_t)(t * 4 + b) * 256;
        float acc = 0.0f;
#pragma unroll
        for (int kh = 0; kh < 3; ++kh) {
            int ih = h - 1 + kh;
            if (ih < 0 || ih >= 16) continue;
#pragma unroll
            for (int kw = 0; kw < 3; ++kw) {
                int iw = w - 1 + kw;
                if (iw < 0 || iw >= 16) continue;
                ull mm64 = mb[ih * 16 + iw];
                unsigned lo = __builtin_amdgcn_readfirstlane((unsigned)mm64);
                unsigned hi = __builtin_amdgcn_readfirstlane((unsigned)(mm64 >> 32));
                ull m = ((ull)hi << 32) | lo;
                sacc<64>(acc, m, wl + (kh * 3 + kw) * 4096 + lane);
            }
        }
        float s = iir_spike_step(acc, y1, y2, xp, r1, r2, sp);
        ull mm = __ballot(s > 0.5f);
        if (lane == 0) s4m[((size_t)(t * 4 + b) * 256 + pix) * 2 + half] = mm;
    }
}

// ---------------- SP3: pool SC3 masks -> pix-packed masks s5m [t][b][c=128] ulong (bit pix)
__global__ void k_sp3(const ull* __restrict__ s4m, ull* __restrict__ s5m) {
    int wid = (blockIdx.x * 256 + threadIdx.x) >> 6;   // b*128 + c
    int lane = threadIdx.x & 63;
    int c = wid & 127;
    int b = wid >> 7;
    int half = c >> 6;
    int cbit = c & 63;
    int ho = lane >> 3, wo = lane & 7;
    float y1 = 0, y2 = 0, xp = 0, r1 = 0, r2 = 0, sp = 0;
    for (int t = 0; t < 100; ++t) {
        const ull* mb = s4m + ((size_t)(t * 4 + b) * 256 + (2 * ho) * 16 + 2 * wo) * 2 + half;
        // input pixels: (2ho,2wo)=+0, (2ho,2wo+1)=+2, (2ho+1,2wo)=+32, (2ho+1,2wo+1)=+34
        ull a0 = mb[0], a1 = mb[2], a2 = mb[32], a3 = mb[34];
        float cnt = (float)(((a0 >> cbit) & 1) + ((a1 >> cbit) & 1) +
                            ((a2 >> cbit) & 1) + ((a3 >> cbit) & 1));
        float s = iir_spike_step(11.0f * cnt, y1, y2, xp, r1, r2, sp);
        ull mm = __ballot(s > 0.5f);
        if (lane == 0) s5m[(size_t)(t * 4 + b) * 128 + c] = mm;
    }
}

// ---------------- SF4a GEMM: acc[tb][512] = sum over active f of wT[f][o], batched walk
__global__ void k_gemm4a(const ull* __restrict__ s5m,
                         const float* __restrict__ wT,
                         float* __restrict__ acc_out) {
    int wg = blockIdx.x * 4 + (threadIdx.x >> 6);   // 3200 waves
    int lane = threadIdx.x & 63;
    int ot = wg & 7;
    int tb = wg >> 3;                               // 0..399
    const ull* mp = s5m + (size_t)tb * 128;
    const float* wbase = wT + ot * 64 + lane;
    float acc = 0.0f;
    for (int c = 0; c < 128; ++c) {
        ull mv = mp[c];
        unsigned lo = __builtin_amdgcn_readfirstlane((unsigned)mv);
        unsigned hi = __builtin_amdgcn_readfirstlane((unsigned)(mv >> 32));
        ull m = ((ull)hi << 32) | lo;
        sacc<512>(acc, m, wbase + (size_t)(c * 64) * 512);
    }
    acc_out[(size_t)tb * 512 + ot * 64 + lane] = acc;
}

// ---------------- SF4a IIR: per-(b,o) scan over precomputed acc -> u8 spikes s6 [t][b][512]
__global__ void k_iir4a(const float* __restrict__ accbuf, unsigned char* __restrict__ s6) {
    int id = blockIdx.x * 64 + threadIdx.x;   // 2048 = b*512+o
    int b = id >> 9, o = id & 511;
    float y1 = 0, y2 = 0, xp = 0, r1 = 0, r2 = 0, sp = 0;
    for (int t = 0; t < 100; ++t) {
        float a = accbuf[(size_t)(t * 4 + b) * 512 + o];
        float s = iir_spike_step(a, y1, y2, xp, r1, r2, sp);
        s6[(size_t)(t * 4 + b) * 512 + o] = (unsigned char)s;
    }
}

// ---------------- SF4b: dense 512->11 -> final out [B][11][T] f32
__global__ void k_dense4b(const unsigned char* __restrict__ in,
                          const float* __restrict__ wt,
                          float* __restrict__ out) {
    int wid = blockIdx.x;      // 44 = (b,o)
    int lane = threadIdx.x;
    int o = wid % 11;
    int b = wid / 11;
    float wreg[8];
    const float* wp = wt + o * 512 + lane * 8;
#pragma unroll
    for (int k = 0; k < 8; ++k) wreg[k] = wp[k];
    float y1 = 0, y2 = 0, xp = 0, r1 = 0, r2 = 0, sp = 0;
    for (int t = 0; t < 100; ++t) {
        const unsigned char* ip = in + (size_t)(t * 4 + b) * 512 + lane * 8;
        uchar4 a = *(const uchar4*)ip;
        uchar4 c = *(const uchar4*)(ip + 4);
        float acc = wreg[0] * (float)a.x + wreg[1] * (float)a.y +
                    wreg[2] * (float)a.z + wreg[3] * (float)a.w +
                    wreg[4] * (float)c.x + wreg[5] * (float)c.y +
                    wreg[6] * (float)c.z + wreg[7] * (float)c.w;
#pragma unroll
        for (int off = 32; off > 0; off >>= 1) acc += __shfl_xor(acc, off, 64);
        float s = iir_spike_step(acc, y1, y2, xp, r1, r2, sp);
        if (lane == 0) out[(b * 11 + o) * 100 + t] = s;
    }
}

extern "C" void kernel_launch(void* const* d_in, const int* in_sizes, int n_in,
                              void* d_out, int out_size, void* d_ws, size_t ws_size,
                              hipStream_t stream) {
    const float* s_in = (const float*)d_in[0];
    const float* w1   = (const float*)d_in[1];
    const float* w2   = (const float*)d_in[2];
    const float* w3   = (const float*)d_in[3];
    const float* w4a  = (const float*)d_in[4];
    const float* w4b  = (const float*)d_in[5];
    float* out = (float*)d_out;

    char* ws = (char*)d_ws;
    ull*           s0m  = (ull*)(ws + 0);              //   409,600
    ull*           s1m  = (ull*)(ws + 409600);         // 6,553,600
    unsigned*      s2m  = (unsigned*)(ws + 6963200);   // 1,638,400
    ull*           sc2m = (ull*)(ws + 8601600);        // 3,276,800
    ull*           s3m  = (ull*)(ws + 11878400);       //   819,200
    ull*           s4m  = (ull*)(ws + 12697600);       // 1,638,400
    ull*           s5m  = (ull*)(ws + 14336000);       //   409,600
    unsigned char* s6   = (unsigned char*)(ws + 14745600);  //   204,800
    float*         accA = (float*)(ws + 14950400);     //   819,200
    float*         w2T  = (float*)(ws + 15769600);     //    73,728
    float*         w3T  = (float*)(ws + 15843328);     //   294,912
    float*         wT4a = (float*)(ws + 16138240);     // 16,777,216  (end ~32.9MB)

    // allow >64KB dynamic LDS for the sparse conv kernels
    hipFuncSetAttribute((const void*)k_sc2, hipFuncAttributeMaxDynamicSharedMemorySize, 73728);
    hipFuncSetAttribute((const void*)k_sc3, hipFuncAttributeMaxDynamicSharedMemorySize, 147456);

    k_wT<<<288, 256, 0, stream>>>(w2, w3, w2T, w3T);
    k_wT4a<<<1024, 256, 0, stream>>>(w4a, wT4a);
    k_sp0<<<128, 256, 0, stream>>>(s_in, s0m);
    k_sc1<<<2048, 256, 0, stream>>>(s0m, w1, s1m);
    k_sp1<<<512, 256, 0, stream>>>(s1m, s2m);
    k_sc2<<<256, 1024, 73728, stream>>>(s2m, w2T, sc2m);
    k_sp2<<<256, 256, 0, stream>>>(sc2m, s3m);
    k_sc3<<<256, 512, 147456, stream>>>(s3m, w3T, s4m);
    k_sp3<<<128, 256, 0, stream>>>(s4m, s5m);
    k_gemm4a<<<800, 256, 0, stream>>>(s5m, wT4a, accA);
    k_iir4a<<<32, 64, 0, stream>>>(accA, s6);
    k_dense4b<<<44, 64, 0, stream>>>(s6, w4b, out);
}

// Round 11
// 1424.356 us; speedup vs baseline: 1.1214x; 1.1214x over previous
//
#include <hip/hip_runtime.h>

typedef unsigned long long ull;

// SLAYER SRM-alpha constants (f64-computed, f32-cast):
__device__ constexpr float C1f = (float)1.80967483607191914632;   // 2*exp(-0.1)
__device__ constexpr float C2f = (float)0.81873075307798185867;   // exp(-0.2)
__device__ constexpr float C3f = (float)0.24596031111569496638;   // e^0.9/10

__device__ __forceinline__ float iir_spike_step(float acc, float& y1, float& y2, float& xp,
                                                float& r1, float& r2, float& sp) {
#pragma clang fp contract(off)
    float u = C1f * y1 - C2f * y2 + C3f * xp;   // psp output at t (uses x[t-1])
    float r = C1f * r1 - C2f * r2 + C3f * sp;   // alpha response to past spikes
    float s = (u - 20.0f * r >= 10.0f) ? 1.0f : 0.0f;
    y2 = y1; y1 = u; xp = acc;
    r2 = r1; r1 = r; sp = s;
    return s;
}

// 4-wide batched sparse accumulate over a wave-uniform mask (measured-best width).
// ptr pre-offset by lane; term for bit c = ptr[c*STRIDE]. Ascending c: bit-exact.
template <int STRIDE>
__device__ __forceinline__ void sacc(float& acc, ull m, const float* __restrict__ ptr) {
    while (m) {
        ull m1 = m & (m - 1);
        ull m2 = m1 & (m1 - 1);
        ull m3 = m2 & (m2 - 1);
        if (m3) {
            int c0 = __builtin_ctzll(m);
            int c1 = __builtin_ctzll(m1);
            int c2 = __builtin_ctzll(m2);
            int c3 = __builtin_ctzll(m3);
            float w0 = ptr[c0 * STRIDE];
            float w1 = ptr[c1 * STRIDE];
            float w2 = ptr[c2 * STRIDE];
            float w3 = ptr[c3 * STRIDE];
            acc += w0; acc += w1; acc += w2; acc += w3;
            m = m3 & (m3 - 1);
        } else {
            acc += ptr[__builtin_ctzll(m) * STRIDE];
            m = m1;
        }
    }
}

// Dual-mask interleaved walk: per round, extract up to 4 bits from EACH mask
// (zero-slot padded -> branch-free, 8 independent LDS loads in flight).
// Pads add +0.0f (exact; acc never -0 here). Per-mask add order ascending c.
__device__ __forceinline__ void sacc2(float& a0, ull m0, float& a1, ull m1,
                                      const float* __restrict__ wl,
                                      int posoff, int zoff, int lane) {
    while (m0 | m1) {
        int i00 = m0 ? posoff + (int)__builtin_ctzll(m0) * 64 + lane : zoff + lane; m0 &= m0 - 1;
        int i01 = m0 ? posoff + (int)__builtin_ctzll(m0) * 64 + lane : zoff + lane; m0 &= m0 - 1;
        int i02 = m0 ? posoff + (int)__builtin_ctzll(m0) * 64 + lane : zoff + lane; m0 &= m0 - 1;
        int i03 = m0 ? posoff + (int)__builtin_ctzll(m0) * 64 + lane : zoff + lane; m0 &= m0 - 1;
        int i10 = m1 ? posoff + (int)__builtin_ctzll(m1) * 64 + lane : zoff + lane; m1 &= m1 - 1;
        int i11 = m1 ? posoff + (int)__builtin_ctzll(m1) * 64 + lane : zoff + lane; m1 &= m1 - 1;
        int i12 = m1 ? posoff + (int)__builtin_ctzll(m1) * 64 + lane : zoff + lane; m1 &= m1 - 1;
        int i13 = m1 ? posoff + (int)__builtin_ctzll(m1) * 64 + lane : zoff + lane; m1 &= m1 - 1;
        float v00 = wl[i00], v01 = wl[i01], v02 = wl[i02], v03 = wl[i03];
        float v10 = wl[i10], v11 = wl[i11], v12 = wl[i12], v13 = wl[i13];
        a0 += v00; a0 += v01; a0 += v02; a0 += v03;
        a1 += v10; a1 += v11; a1 += v12; a1 += v13;
    }
}

// ---------------- SP0: pool(2x2 of s_in) + psp + spike -> w-packed row masks
__global__ void k_sp0(const float* __restrict__ s_in, ull* __restrict__ s0m) {
    int wid = (blockIdx.x * 256 + threadIdx.x) >> 6;   // 0..511 = (b,c,h)
    int lane = threadIdx.x & 63;                        // w
    int h = wid & 63;
    int c = (wid >> 6) & 1;
    int b = wid >> 7;
    const float* p00 = s_in + ((size_t)(((b * 2 + c) * 128 + 2 * h) * 128 + 2 * lane)) * 100;
    const float* p01 = p00 + 100;
    const float* p10 = p00 + 12800;
    const float* p11 = p10 + 100;
    float y1 = 0, y2 = 0, xp = 0, r1 = 0, r2 = 0, sp = 0;
    for (int t = 0; t < 100; ++t) {
        float cnt = (p00[t] > 0.5f) + (p01[t] > 0.5f) + (p10[t] > 0.5f) + (p11[t] > 0.5f);
        float s = iir_spike_step(11.0f * cnt, y1, y2, xp, r1, r2, sp);
        ull m = __ballot(s > 0.5f);
        if (lane == 0) s0m[((size_t)(t * 4 + b) * 2 + c) * 64 + h] = m;
    }
}

// ---------------- SC1: 5x5 conv (2ch) via register weights + bit-FMA (no LDS)
// s1m layout: [t][b][h][o] ulong (bit w) -> coalesced consumption in SP1.
__global__ void k_sc1(const ull* __restrict__ s0m, const float* __restrict__ w1,
                      ull* __restrict__ s1m) {
    int hg = blockIdx.x & 15;
    int o  = (blockIdx.x >> 4) & 31;
    int b  = blockIdx.x >> 9;
    float wr[50];                           // wave-uniform -> regs
#pragma unroll
    for (int i = 0; i < 50; ++i) wr[i] = w1[o * 50 + i];
    int h = hg * 4 + (threadIdx.x >> 6);
    int lane = threadIdx.x & 63;            // w
    int sh = lane - 2;
    float y1 = 0, y2 = 0, xp = 0, r1 = 0, r2 = 0, sp = 0;
    for (int t = 0; t < 100; ++t) {
        float acc = 0.0f;
        const ull* rb = s0m + (size_t)(t * 4 + b) * 128;
#pragma unroll
        for (int c = 0; c < 2; ++c) {
#pragma unroll
            for (int kh = 0; kh < 5; ++kh) {
                int ih = h - 2 + kh;
                ull m = (ih >= 0 && ih < 64) ? rb[c * 64 + ih] : 0ULL;
                unsigned pat = (sh >= 0) ? ((unsigned)(m >> sh) & 31u)
                                         : (((unsigned)m << (-sh)) & 31u);
#pragma unroll
                for (int j = 0; j < 5; ++j)                     // ascending kw, exact
                    acc = fmaf((float)((pat >> j) & 1u), wr[c * 25 + kh * 5 + j], acc);
            }
        }
        float s = iir_spike_step(acc, y1, y2, xp, r1, r2, sp);
        ull mm = __ballot(s > 0.5f);
        if (lane == 0) s1m[((size_t)(t * 4 + b) * 64 + h) * 32 + o] = mm;
    }
}

// ---------------- SP1: pool SC1 spikes -> c-packed masks s2m [t][b][32][32] uint (bit c)
__global__ void k_sp1(const ull* __restrict__ s1m, unsigned* __restrict__ s2m) {
    int wid = (blockIdx.x * 256 + threadIdx.x) >> 6;   // (b*32+ho)*16+wop
    int lane = threadIdx.x & 63;
    int wop = wid & 15;
    int ho = (wid >> 4) & 31;
    int b = wid >> 9;
    int c = lane & 31;
    int q = lane >> 5;
    int w = wop * 2 + q;                                // output wo
    float y1 = 0, y2 = 0, xp = 0, r1 = 0, r2 = 0, sp = 0;
    for (int t = 0; t < 100; ++t) {
        const ull* base = s1m + ((size_t)(t * 4 + b) * 64 + 2 * ho) * 32 + c;
        ull m0 = base[0], m1 = base[32];
        unsigned v0 = (unsigned)(m0 >> (2 * w)) & 3u;
        unsigned v1 = (unsigned)(m1 >> (2 * w)) & 3u;
        float cnt = (float)((v0 & 1) + (v0 >> 1) + (v1 & 1) + (v1 >> 1));
        float s = iir_spike_step(11.0f * cnt, y1, y2, xp, r1, r2, sp);
        ull mm = __ballot(s > 0.5f);
        if (lane == 0)  s2m[((size_t)(t * 4 + b) * 32 + ho) * 32 + wop * 2]     = (unsigned)mm;
        if (lane == 32) s2m[((size_t)(t * 4 + b) * 32 + ho) * 32 + wop * 2 + 1] = (unsigned)(mm >> 32);
    }
}

// ---------------- weight transposes into ws: wT[pos][c][o]
__global__ void k_wT(const float* __restrict__ w2, const float* __restrict__ w3,
                     float* __restrict__ w2T, float* __restrict__ w3T) {
    int i = blockIdx.x * 256 + threadIdx.x;
    if (i < 9 * 32 * 64) {
        int o = i & 63; int c = (i >> 6) & 31; int p = i >> 11;
        w2T[i] = w2[(o * 32 + c) * 9 + p];
    }
    if (i < 9 * 64 * 128) {
        int o = i & 127; int c = (i >> 7) & 63; int p = i >> 13;
        w3T[i] = w3[(o * 64 + c) * 9 + p];
    }
}

// ---------------- transpose wf4a [512][8192] -> wT4a [8192][512], 64x64 LDS tiles
__global__ void k_wT4a(const float* __restrict__ w, float* __restrict__ wT) {
    __shared__ float tile[64][65];
    int ft = blockIdx.x & 127;   // f tile
    int ot = blockIdx.x >> 7;    // o tile (0..7)
    int j = threadIdx.x & 63;
    int i0 = threadIdx.x >> 6;   // 0..3
    for (int i = i0; i < 64; i += 4)
        tile[i][j] = w[(size_t)(ot * 64 + i) * 8192 + ft * 64 + j];
    __syncthreads();
    for (int i = i0; i < 64; i += 4)
        wT[(size_t)(ft * 64 + i) * 512 + ot * 64 + j] = tile[j][i];
}

// ---------------- SC2: sparse 3x3 conv (32c -> 64o), full-LDS weights + t-pair walk
// 256 blocks x 1024 thr (16 waves). LDS 72KB + 256B zero pad -> 2 blocks/CU.
__global__ __launch_bounds__(1024) void k_sc2(const unsigned* __restrict__ s2m,
                                              const float* __restrict__ w2T,
                                              ull* __restrict__ sc2m) {
    extern __shared__ float wl[];
    const int ZOFF = 9 * 32 * 64;                      // 18432
    for (int i = threadIdx.x; i < ZOFF; i += 1024) wl[i] = w2T[i];
    if (threadIdx.x < 64) wl[ZOFF + threadIdx.x] = 0.0f;
    __syncthreads();
    int task = blockIdx.x * 16 + (threadIdx.x >> 6);   // 0..4095
    int pix = task & 1023;
    int b = task >> 10;
    int h = pix >> 5, w = pix & 31;
    int lane = threadIdx.x & 63;   // o
    float y1 = 0, y2 = 0, xp = 0, r1 = 0, r2 = 0, sp = 0;
    for (int t = 0; t < 100; t += 2) {
        const unsigned* mbA = s2m + (size_t)(t * 4 + b) * 1024;
        const unsigned* mbB = mbA + 4096;              // t+1
        float acc0 = 0.0f, acc1 = 0.0f;
#pragma unroll
        for (int kh = 0; kh < 3; ++kh) {
            int ih = h - 1 + kh;
            if (ih < 0 || ih >= 32) continue;
#pragma unroll
            for (int kw = 0; kw < 3; ++kw) {
                int iw = w - 1 + kw;
                if (iw < 0 || iw >= 32) continue;
                unsigned mA = __builtin_amdgcn_readfirstlane(mbA[ih * 32 + iw]);
                unsigned mB = __builtin_amdgcn_readfirstlane(mbB[ih * 32 + iw]);
                sacc2(acc0, (ull)mA, acc1, (ull)mB, wl, (kh * 3 + kw) * 2048, ZOFF, lane);
            }
        }
        float s0 = iir_spike_step(acc0, y1, y2, xp, r1, r2, sp);
        ull mm0 = __ballot(s0 > 0.5f);
        if (lane == 0) sc2m[(size_t)(t * 4 + b) * 1024 + pix] = mm0;
        float s1 = iir_spike_step(acc1, y1, y2, xp, r1, r2, sp);
        ull mm1 = __ballot(s1 > 0.5f);
        if (lane == 0) sc2m[(size_t)((t + 1) * 4 + b) * 1024 + pix] = mm1;
    }
}

// ---------------- SP2: pool SC2 masks -> s3m [t][b][16][16] ulong (bit c of 64)
__global__ void k_sp2(const ull* __restrict__ sc2m, ull* __restrict__ s3m) {
    int wid = (blockIdx.x * 256 + threadIdx.x) >> 6;   // (b*16+ho)*16+wo
    int lane = threadIdx.x & 63;                        // c
    int wo = wid & 15;
    int ho = (wid >> 4) & 15;
    int b = wid >> 8;
    float y1 = 0, y2 = 0, xp = 0, r1 = 0, r2 = 0, sp = 0;
    for (int t = 0; t < 100; ++t) {
        const ull* mb = sc2m + (size_t)(t * 4 + b) * 1024 + (2 * ho) * 32 + 2 * wo;
        ull a0 = mb[0], a1 = mb[1], a2 = mb[32], a3 = mb[33];
        float cnt = (float)(((a0 >> lane) & 1) + ((a1 >> lane) & 1) +
                            ((a2 >> lane) & 1) + ((a3 >> lane) & 1));
        float s = iir_spike_step(11.0f * cnt, y1, y2, xp, r1, r2, sp);
        ull mm = __ballot(s > 0.5f);
        if (lane == 0) s3m[(size_t)(t * 4 + b) * 256 + ho * 16 + wo] = mm;
    }
}

// ---------------- SC3: sparse 3x3 conv (64c -> 128o, o-half per block), full-LDS + t-pair
// 256 blocks x 512 thr (8 waves). LDS 144KB + 256B zero pad, 1 block/CU.
__global__ __launch_bounds__(512) void k_sc3(const ull* __restrict__ s3m,
                                             const float* __restrict__ w3T,
                                             ull* __restrict__ s4m) {
    extern __shared__ float wl[];
    const int ZOFF = 9 * 64 * 64;                      // 36864
    int half = blockIdx.x & 1;
    int rest = blockIdx.x >> 1;          // 0..127 = b*32 + pg
    int pg = rest & 31;
    int b = rest >> 5;
    for (int i = threadIdx.x; i < ZOFF; i += 512) {
        int o = i & 63; int pc = i >> 6;               // pc = p*64+c
        wl[i] = w3T[pc * 128 + half * 64 + o];
    }
    if (threadIdx.x < 64) wl[ZOFF + threadIdx.x] = 0.0f;
    __syncthreads();
    int pix = pg * 8 + (threadIdx.x >> 6);
    int h = pix >> 4, w = pix & 15;
    int lane = threadIdx.x & 63;   // o within half
    float y1 = 0, y2 = 0, xp = 0, r1 = 0, r2 = 0, sp = 0;
    for (int t = 0; t < 100; t += 2) {
        const ull* mbA = s3m + (size_t)(t * 4 + b) * 256;
        const ull* mbB = mbA + 1024;                   // t+1
        float acc0 = 0.0f, acc1 = 0.0f;
#pragma unroll
        for (int kh = 0; kh < 3; ++kh) {
            int ih = h - 1 + kh;
            if (ih < 0 || ih >= 16) continue;
#pragma unroll
            for (int kw = 0; kw < 3; ++kw) {
                int iw = w - 1 + kw;
                if (iw < 0 || iw >= 16) continue;
                ull mA64 = mbA[ih * 16 + iw];
                ull mB64 = mbB[ih * 16 + iw];
                unsigned loA = __builtin_amdgcn_readfirstlane((unsigned)mA64);
                unsigned hiA = __builtin_amdgcn_readfirstlane((unsigned)(mA64 >> 32));
                unsigned loB = __builtin_amdgcn_readfirstlane((unsigned)mB64);
                unsigned hiB = __builtin_amdgcn_readfirstlane((unsigned)(mB64 >> 32));
                ull mA = ((ull)hiA << 32) | loA;
                ull mB = ((ull)hiB << 32) | loB;
                sacc2(acc0, mA, acc1, mB, wl, (kh * 3 + kw) * 4096, ZOFF, lane);
            }
        }
        float s0 = iir_spike_step(acc0, y1, y2, xp, r1, r2, sp);
        ull mm0 = __ballot(s0 > 0.5f);
        if (lane == 0) s4m[((size_t)(t * 4 + b) * 256 + pix) * 2 + half] = mm0;
        float s1 = iir_spike_step(acc1, y1, y2, xp, r1, r2, sp);
        ull mm1 = __ballot(s1 > 0.5f);
        if (lane == 0) s4m[((size_t)((t + 1) * 4 + b) * 256 + pix) * 2 + half] = mm1;
    }
}

// ---------------- SP3: pool SC3 masks -> pix-packed masks s5m [t][b][c=128] ulong (bit pix)
__global__ void k_sp3(const ull* __restrict__ s4m, ull* __restrict__ s5m) {
    int wid = (blockIdx.x * 256 + threadIdx.x) >> 6;   // b*128 + c
    int lane = threadIdx.x & 63;
    int c = wid & 127;
    int b = wid >> 7;
    int half = c >> 6;
    int cbit = c & 63;
    int ho = lane >> 3, wo = lane & 7;
    float y1 = 0, y2 = 0, xp = 0, r1 = 0, r2 = 0, sp = 0;
    for (int t = 0; t < 100; ++t) {
        const ull* mb = s4m + ((size_t)(t * 4 + b) * 256 + (2 * ho) * 16 + 2 * wo) * 2 + half;
        // input pixels: (2ho,2wo)=+0, (2ho,2wo+1)=+2, (2ho+1,2wo)=+32, (2ho+1,2wo+1)=+34
        ull a0 = mb[0], a1 = mb[2], a2 = mb[32], a3 = mb[34];
        float cnt = (float)(((a0 >> cbit) & 1) + ((a1 >> cbit) & 1) +
                            ((a2 >> cbit) & 1) + ((a3 >> cbit) & 1));
        float s = iir_spike_step(11.0f * cnt, y1, y2, xp, r1, r2, sp);
        ull mm = __ballot(s > 0.5f);
        if (lane == 0) s5m[(size_t)(t * 4 + b) * 128 + c] = mm;
    }
}

// ---------------- SF4a GEMM: acc[tb][512] = sum over active f of wT[f][o], 4-deep walk
__global__ void k_gemm4a(const ull* __restrict__ s5m,
                         const float* __restrict__ wT,
                         float* __restrict__ acc_out) {
    int wg = blockIdx.x * 4 + (threadIdx.x >> 6);   // 3200 waves
    int lane = threadIdx.x & 63;
    int ot = wg & 7;
    int tb = wg >> 3;                               // 0..399
    const ull* mp = s5m + (size_t)tb * 128;
    const float* wbase = wT + ot * 64 + lane;
    float acc = 0.0f;
    for (int c = 0; c < 128; ++c) {
        ull mv = mp[c];
        unsigned lo = __builtin_amdgcn_readfirstlane((unsigned)mv);
        unsigned hi = __builtin_amdgcn_readfirstlane((unsigned)(mv >> 32));
        ull m = ((ull)hi << 32) | lo;
        sacc<512>(acc, m, wbase + (size_t)(c * 64) * 512);
    }
    acc_out[(size_t)tb * 512 + ot * 64 + lane] = acc;
}

// ---------------- SF4a IIR: per-(b,o) scan over precomputed acc -> u8 spikes s6 [t][b][512]
__global__ void k_iir4a(const float* __restrict__ accbuf, unsigned char* __restrict__ s6) {
    int id = blockIdx.x * 64 + threadIdx.x;   // 2048 = b*512+o
    int b = id >> 9, o = id & 511;
    float y1 = 0, y2 = 0, xp = 0, r1 = 0, r2 = 0, sp = 0;
    for (int t = 0; t < 100; ++t) {
        float a = accbuf[(size_t)(t * 4 + b) * 512 + o];
        float s = iir_spike_step(a, y1, y2, xp, r1, r2, sp);
        s6[(size_t)(t * 4 + b) * 512 + o] = (unsigned char)s;
    }
}

// ---------------- SF4b: dense 512->11 -> final out [B][11][T] f32
__global__ void k_dense4b(const unsigned char* __restrict__ in,
                          const float* __restrict__ wt,
                          float* __restrict__ out) {
    int wid = blockIdx.x;      // 44 = (b,o)
    int lane = threadIdx.x;
    int o = wid % 11;
    int b = wid / 11;
    float wreg[8];
    const float* wp = wt + o * 512 + lane * 8;
#pragma unroll
    for (int k = 0; k < 8; ++k) wreg[k] = wp[k];
    float y1 = 0, y2 = 0, xp = 0, r1 = 0, r2 = 0, sp = 0;
    for (int t = 0; t < 100; ++t) {
        const unsigned char* ip = in + (size_t)(t * 4 + b) * 512 + lane * 8;
        uchar4 a = *(const uchar4*)ip;
        uchar4 c = *(const uchar4*)(ip + 4);
        float acc = wreg[0] * (float)a.x + wreg[1] * (float)a.y +
                    wreg[2] * (float)a.z + wreg[3] * (float)a.w +
                    wreg[4] * (float)c.x + wreg[5] * (float)c.y +
                    wreg[6] * (float)c.z + wreg[7] * (float)c.w;
#pragma unroll
        for (int off = 32; off > 0; off >>= 1) acc += __shfl_xor(acc, off, 64);
        float s = iir_spike_step(acc, y1, y2, xp, r1, r2, sp);
        if (lane == 0) out[(b * 11 + o) * 100 + t] = s;
    }
}

extern "C" void kernel_launch(void* const* d_in, const int* in_sizes, int n_in,
                              void* d_out, int out_size, void* d_ws, size_t ws_size,
                              hipStream_t stream) {
    const float* s_in = (const float*)d_in[0];
    const float* w1   = (const float*)d_in[1];
    const float* w2   = (const float*)d_in[2];
    const float* w3   = (const float*)d_in[3];
    const float* w4a  = (const float*)d_in[4];
    const float* w4b  = (const float*)d_in[5];
    float* out = (float*)d_out;

    char* ws = (char*)d_ws;
    ull*           s0m  = (ull*)(ws + 0);              //   409,600
    ull*           s1m  = (ull*)(ws + 409600);         // 6,553,600
    unsigned*      s2m  = (unsigned*)(ws + 6963200);   // 1,638,400
    ull*           sc2m = (ull*)(ws + 8601600);        // 3,276,800
    ull*           s3m  = (ull*)(ws + 11878400);       //   819,200
    ull*           s4m  = (ull*)(ws + 12697600);       // 1,638,400
    ull*           s5m  = (ull*)(ws + 14336000);       //   409,600
    unsigned char* s6   = (unsigned char*)(ws + 14745600);  //   204,800
    float*         accA = (float*)(ws + 14950400);     //   819,200
    float*         w2T  = (float*)(ws + 15769600);     //    73,728
    float*         w3T  = (float*)(ws + 15843328);     //   294,912
    float*         wT4a = (float*)(ws + 16138240);     // 16,777,216  (end ~32.9MB)

    // allow >64KB dynamic LDS for the sparse conv kernels (+256B zero pad)
    hipFuncSetAttribute((const void*)k_sc2, hipFuncAttributeMaxDynamicSharedMemorySize, 73984);
    hipFuncSetAttribute((const void*)k_sc3, hipFuncAttributeMaxDynamicSharedMemorySize, 147712);

    k_wT<<<288, 256, 0, stream>>>(w2, w3, w2T, w3T);
    k_wT4a<<<1024, 256, 0, stream>>>(w4a, wT4a);
    k_sp0<<<128, 256, 0, stream>>>(s_in, s0m);
    k_sc1<<<2048, 256, 0, stream>>>(s0m, w1, s1m);
    k_sp1<<<512, 256, 0, stream>>>(s1m, s2m);
    k_sc2<<<256, 1024, 73984, stream>>>(s2m, w2T, sc2m);
    k_sp2<<<256, 256, 0, stream>>>(sc2m, s3m);
    k_sc3<<<256, 512, 147712, stream>>>(s3m, w3T, s4m);
    k_sp3<<<128, 256, 0, stream>>>(s4m, s5m);
    k_gemm4a<<<800, 256, 0, stream>>>(s5m, wT4a, accA);
    k_iir4a<<<32, 64, 0, stream>>>(accA, s6);
    k_dense4b<<<44, 64, 0, stream>>>(s6, w4b, out);
}